// Round 21
// baseline (630.763 us; speedup 1.0000x reference)
//
#include <hip/hip_runtime.h>
#include <hip/hip_bf16.h>

using short8 = __attribute__((ext_vector_type(8))) short;
using s4_    = __attribute__((ext_vector_type(4))) short;
using f32x4  = __attribute__((ext_vector_type(4))) float;

// Problem dims
#define B_     1024
#define NLEV_  60
#define NBLK_  64     // batch blocks for LSTM kernels
#define ROWS_  16     // batch rows per block
#define QLEV_  15     // levels per lstm2 quarter

#define AS1(p) ((const __attribute__((address_space(1))) void*)(p))
#define AS3(p) ((__attribute__((address_space(3))) void*)(p))

__device__ __forceinline__ float bf2f(unsigned short u){
  unsigned int v = ((unsigned int)u) << 16;
  return __builtin_bit_cast(float, v);
}
__device__ __forceinline__ unsigned short f2bf(float x){
  __hip_bfloat16 h = __float2bfloat16(x);
  return __builtin_bit_cast(unsigned short, h);
}
__device__ __forceinline__ float sigm_(float x){
  return __builtin_amdgcn_rcpf(1.0f + __expf(-x));
}
__device__ __forceinline__ float tanh_(float x){
  return 1.0f - 2.0f*__builtin_amdgcn_rcpf(1.0f + __expf(2.0f*x));
}
// Barrier that does NOT drain vmcnt: LDS-visibility only.
__device__ __forceinline__ void softbar(){
  asm volatile("s_waitcnt lgkmcnt(0)" ::: "memory");
  __builtin_amdgcn_s_barrier();
  asm volatile("" ::: "memory");
}

// ---------------------------------------------------------------------------
// prep_weights: f32 -> bf16 MFMA B-frag CHUNK layout for the LDS-ring
// streaming kernels. A frag = 64 lanes x 8 shorts (1024 B); lane l holds
// W[n=16nt+(l&15)][k=32kf+8*(l>>4)+j].
// f_all1 (lstm1): 7 chunks of 48 frags: chunk0 = Wih1 (K=28 pad 32),
//                 chunk 1+kf = Whh1 kf. f_all2 (lstm2r): 6 chunks = Whh2 kf.
// f_ih2 (xg_gemm): frag (nt,kf) at (nt*6+kf)*64+lane.
// ---------------------------------------------------------------------------
__global__ void prep_weights_k(const float* __restrict__ Whh1, const float* __restrict__ Wih1,
                               const float* __restrict__ Whh2, const float* __restrict__ Wih2,
                               unsigned short* __restrict__ f_all1, unsigned short* __restrict__ f_all2,
                               unsigned short* __restrict__ f_ih2){
  int t = blockIdx.x*256 + threadIdx.x;
  if (t >= 912*64) return;
  int lane = t & 63;
  int fr   = t >> 6;
  int m    = lane & 15;
  int g16  = lane >> 4;
  short8 sv;
  unsigned short* dst;
  if (fr < 48){                     // Wih1 -> f_all1 chunk 0
    int nt = fr;
    int n = nt*16 + m, k0 = g16*8;
    #pragma unroll
    for (int j=0;j<8;j++){
      int k = k0 + j;
      sv[j] = (short)((k < 28) ? f2bf(Wih1[n*28 + k]) : (unsigned short)0);
    }
    dst = f_all1 + ((size_t)(0*48 + nt)*64 + lane)*8;
  } else if (fr < 336){             // Whh1 -> f_all1 chunks 1..6
    int q = fr - 48;
    int kf = q/48, nt = q%48;
    int n = nt*16 + m, k0 = kf*32 + g16*8;
    #pragma unroll
    for (int j=0;j<8;j++) sv[j] = (short)f2bf(Whh1[n*192 + k0 + j]);
    dst = f_all1 + ((size_t)((1+kf)*48 + nt)*64 + lane)*8;
  } else if (fr < 624){             // Whh2 -> f_all2 chunks 0..5
    int q = fr - 336;
    int kf = q/48, nt = q%48;
    int n = nt*16 + m, k0 = kf*32 + g16*8;
    #pragma unroll
    for (int j=0;j<8;j++) sv[j] = (short)f2bf(Whh2[n*192 + k0 + j]);
    dst = f_all2 + ((size_t)(kf*48 + nt)*64 + lane)*8;
  } else {                          // Wih2 -> f_ih2
    int fl = fr - 624;
    int nt = fl/6, kf = fl%6;
    int n = nt*16 + m, k0 = kf*32 + g16*8;
    #pragma unroll
    for (int j=0;j<8;j++) sv[j] = (short)f2bf(Wih2[n*192 + k0 + j]);
    dst = f_ih2 + (size_t)(fl*64 + lane)*8;
  }
  *(short8*)dst = sv;
}

// ---------------------------------------------------------------------------
// wc_k
// ---------------------------------------------------------------------------
__global__ void wc_k(const float* __restrict__ W_lat, const float* __restrict__ b_lat,
                     const float* __restrict__ W_out, const float* __restrict__ b_out,
                     float* __restrict__ Wc, float* __restrict__ outb){
  int t = blockIdx.x*256 + threadIdx.x;
  if (t < 960){
    int n = t / 192, k = t % 192;
    float a = 0.f;
    #pragma unroll
    for (int j=0;j<16;j++) a += W_out[n*16+j] * W_lat[j*192+k];
    Wc[t] = a;
  } else if (t < 965){
    int n = t - 960;
    float a = b_out[n];
    #pragma unroll
    for (int j=0;j<16;j++) a += W_out[n*16+j] * b_lat[j];
    outb[n] = a;
  }
}

// ---------------------------------------------------------------------------
// prep_x
// ---------------------------------------------------------------------------
__global__ void prep_x_k(const float* __restrict__ x_lev, const float* __restrict__ xmean_lev,
                         const float* __restrict__ xdiv_lev, const float* __restrict__ memv,
                         unsigned short* __restrict__ xfrag){
  int t = blockIdx.x*256 + threadIdx.x;
  if (t >= NBLK_*NLEV_*64) return;
  int lane = t & 63;
  int lev  = (t >> 6) % NLEV_;
  int blk  = t / (NLEV_*64);
  int m    = lane & 15;
  int b    = blk*ROWS_ + m;
  int k0   = (lane >> 4)*8;
  short8 sv;
  #pragma unroll
  for (int j=0;j<8;j++){
    int k = k0 + j;
    float val = 0.0f;
    if (k < 12)      val = (x_lev[(size_t)(b*NLEV_+lev)*15 + k] - xmean_lev[lev*15+k]) / xdiv_lev[lev*15+k];
    else if (k < 28) val = memv[(size_t)(b*NLEV_+lev)*16 + (k-12)];
    sv[j] = (short)f2bf(val);
  }
  *(short8*)(xfrag + (size_t)((blk*NLEV_+lev)*64 + lane)*8) = sv;
}

// ---------------------------------------------------------------------------
// init_states
// ---------------------------------------------------------------------------
__global__ void init_states_k(const float* __restrict__ x_sfc, const float* __restrict__ xmean_sca,
                              const float* __restrict__ xdiv_sca,
                              const float* __restrict__ Ws1, const float* __restrict__ bs1,
                              const float* __restrict__ Ws2, const float* __restrict__ bs2,
                              const float* __restrict__ Wt1, const float* __restrict__ bt1,
                              const float* __restrict__ Wt2, const float* __restrict__ bt2,
                              float* __restrict__ h0, float* __restrict__ c0,
                              float* __restrict__ h0b, float* __restrict__ c0b){
  int t = blockIdx.x*256 + threadIdx.x;
  if (t >= B_*192) return;
  int b = t / 192, n = t % 192;
  float a1 = bs1[n], a2 = bs2[n];
  for (int j=0;j<19;j++){
    float xs = (x_sfc[b*24+j] - xmean_sca[j]) / xdiv_sca[j];
    a1 += xs * Ws1[n*19+j];
    a2 += xs * Ws2[n*19+j];
  }
  h0[t] = tanh_(a1); c0[t] = tanh_(a2);
  float a3 = bt1[n], a4 = bt2[n];
  for (int j=0;j<2;j++){
    float xt = (x_sfc[b*24+j] - xmean_sca[j]) / xdiv_sca[j];
    a3 += xt * Wt1[n*2+j];
    a4 += xt * Wt2[n*2+j];
  }
  h0b[t] = tanh_(a3); c0b[t] = tanh_(a4);
}

// ---------------------------------------------------------------------------
// lstm1: persistent reverse LSTM, weights streamed via 3-buffer LDS ring
// (global_load_lds DMA). Slot = {wait(W)+barrier, issue, [extras@ch1], MFMA}.
// r20 lesson (THE bug): f_all1 holds only 7 chunks (one step's weights,
// reused every step) — the DMA SOURCE must be chunk gidx%7; the ring BUFFER
// is gidx%3. r17/r19/r20 used gidx%(7*60) for the source -> OOB garbage.
// Wait rule (loads-only, region-based): W2 = 4 ring + 1 ax = 5; else 4.
// LDS: 3x49152 + 12800 = 160256 B.
// ---------------------------------------------------------------------------
__global__ __launch_bounds__(768, 1) void lstm1_k(
    const float* __restrict__ h0, const float* __restrict__ c0,
    const unsigned short* __restrict__ f_all1,
    const unsigned short* __restrict__ xfrag, const float* __restrict__ b1,
    unsigned short* __restrict__ y1frag){
  __shared__ alignas(16) unsigned short h_s[2][16][200];
  __shared__ alignas(16) unsigned short wbuf[3][48*512];
  int tid = threadIdx.x;
  int w = tid >> 6, l = tid & 63;
  int blk = blockIdx.x, b0 = blk*ROWS_;
  int m = l & 15, g4 = l >> 4, m0 = g4*4;
  int col = w*16 + m;
  // all-thread y1 store mapping: 8B per thread per level (6144 B total)
  int sq  = tid*4;
  int skf = sq >> 9, srem = sq & 511;
  int sli = srem >> 3, sj0 = srem & 7;
  int shrow = sli & 15, shcol = skf*32 + (sli>>4)*8 + sj0;

  auto issue1 = [&](int gidx){
    int src = gidx % 7;                 // weights cycle every step (7 chunks)
    int buf = gidx % 3;                 // ring slot
    const unsigned short* g = f_all1 + (size_t)src*48*512 + (size_t)(w*4)*512 + (size_t)l*8;
    unsigned short* lp = &wbuf[buf][(w*4)*512];
    #pragma unroll
    for (int r=0; r<4; r++)
      __builtin_amdgcn_global_load_lds(AS1(g + r*512), AS3(lp + r*512), 16, 0, 0);
  };

  float bias[4];
  #pragma unroll
  for (int g=0; g<4; g++) bias[g] = b1[g*192 + col];
  float c[4];
  #pragma unroll
  for (int r=0; r<4; r++){
    c[r] = c0[(size_t)(b0+m0+r)*192 + col];
    h_s[0][m0+r][col] = f2bf(h0[(size_t)(b0+m0+r)*192 + col]);
  }
  const short8* xfp = (const short8*)xfrag + (size_t)blk*NLEV_*64;
  short8 ax = xfp[(NLEV_-1)*64 + l];   // level for t=0
  issue1(0);
  issue1(1);
  __syncthreads();                     // full drain: chunks 0,1 landed

  int gc = 0;
  for (int t=0; t<NLEV_; t++){
    int cur = t & 1;
    int lsrc = NLEV_-1 - t;
    short8 ax_n = ax;
    f32x4 acc[4];
    #pragma unroll
    for (int g=0; g<4; g++){ acc[g][0]=bias[g]; acc[g][1]=bias[g]; acc[g][2]=bias[g]; acc[g][3]=bias[g]; }
    #pragma unroll
    for (int ch=0; ch<7; ch++){
      if (ch == 2) asm volatile("s_waitcnt vmcnt(5) lgkmcnt(0)" ::: "memory");
      else         asm volatile("s_waitcnt vmcnt(4) lgkmcnt(0)" ::: "memory");
      __builtin_amdgcn_s_barrier();
      asm volatile("" ::: "memory");
      issue1(gc+2);
      if (ch == 1){
        // extras (uniform for ALL waves): ax prefetch + deferred y1 store
        ax_n = xfp[(lsrc > 0 ? lsrc-1 : 0)*64 + l];
        int tprev = (t > 0) ? t-1 : 0;
        int lstore = NLEV_-1 - tprev;  // t=0 dummy -> level 59 (overwritten at t=1)
        s4_ v = *(const s4_*)&h_s[t & 1][shrow][shcol];
        *(s4_*)(y1frag + ((size_t)(blk*NLEV_+lstore)*6 + skf)*512 + (size_t)sli*8 + sj0) = v;
      }
      const short8* wb = (const short8*)&wbuf[gc%3][0];
      if (ch == 0){
        #pragma unroll
        for (int g=0; g<4; g++)
          acc[g] = __builtin_amdgcn_mfma_f32_16x16x32_bf16(ax, wb[(12*g + w)*64 + l], acc[g], 0, 0, 0);
      } else {
        short8 ah = *(const short8*)&h_s[cur][m][(ch-1)*32 + g4*8];
        #pragma unroll
        for (int g=0; g<4; g++)
          acc[g] = __builtin_amdgcn_mfma_f32_16x16x32_bf16(ah, wb[(12*g + w)*64 + l], acc[g], 0, 0, 0);
      }
      gc++;
    }
    #pragma unroll
    for (int r=0; r<4; r++){
      float gi=acc[0][r], gf=acc[1][r], gg=acc[2][r], go=acc[3][r];
      float cn = sigm_(gf)*c[r] + sigm_(gi)*tanh_(gg);
      float hn = sigm_(go)*tanh_(cn);
      c[r] = cn;
      h_s[cur^1][m0+r][col] = f2bf(hn);
    }
    // h_s handoff visibility is provided by next step's slot-0 wait+barrier
    ax = ax_n;
  }
  softbar();
  // final deferred y1 store: step 59's h (in h_s[0]) -> level 0
  {
    s4_ v = *(const s4_*)&h_s[0][shrow][shcol];
    *(s4_*)(y1frag + ((size_t)(blk*NLEV_))*6*512 + (size_t)skf*512 + (size_t)sli*8 + sj0) = v;
  }
}

// ---------------------------------------------------------------------------
// xg_gemm: batch-parallel xg2 = y1 @ W_ih2^T + b2 for QLEV_ levels from lev0.
// 320 blocks x 12 waves; 3 levels per block. (r16 proven)
// ---------------------------------------------------------------------------
__global__ __launch_bounds__(768, 1) void xg_gemm_k(
    const unsigned short* __restrict__ y1frag, const unsigned short* __restrict__ f_ih2,
    const float* __restrict__ b2, float* __restrict__ xgq, int lev0){
  int tid = threadIdx.x;
  int w = tid >> 6, l = tid & 63;
  int blk = blockIdx.x / 5, lg = blockIdx.x % 5;
  const short8* yfp   = (const short8*)y1frag;
  const short8* wih_p = (const short8*)f_ih2;
  f32x4 acc[3][4];
  #pragma unroll
  for (int g=0; g<4; g++){
    float bv = b2[g*192 + 16*w + (l&15)];
    #pragma unroll
    for (int j=0; j<3; j++){ acc[j][g][0]=bv; acc[j][g][1]=bv; acc[j][g][2]=bv; acc[j][g][3]=bv; }
  }
  #pragma unroll
  for (int kf=0; kf<6; kf++){
    short8 wb[4];
    #pragma unroll
    for (int g=0; g<4; g++) wb[g] = wih_p[((12*g + w)*6 + kf)*64 + l];
    #pragma unroll
    for (int j=0; j<3; j++){
      short8 ay = yfp[((size_t)(blk*NLEV_ + lev0 + lg*3 + j)*6 + kf)*64 + l];
      #pragma unroll
      for (int g=0; g<4; g++)
        acc[j][g] = __builtin_amdgcn_mfma_f32_16x16x32_bf16(ay, wb[g], acc[j][g], 0, 0, 0);
    }
  }
  #pragma unroll
  for (int j=0; j<3; j++){
    int tl = lg*3 + j;
    #pragma unroll
    for (int g=0; g<4; g++)
      *(f32x4*)&xgq[(((size_t)blk*QLEV_ + tl)*48 + 12*g + w)*256 + (size_t)l*4] = acc[j][g];
  }
}

// ---------------------------------------------------------------------------
// lstm2r: recurrent-only forward LSTM over QLEV_ steps; Whh2 streamed via
// the same LDS ring (6 chunks/step; source = gidx%6, buffer = gidx%3 —
// already correct in r19/r20). Extras at slot 1: xgn (4 loads) + deferred
// all-thread y2 store. Region-rule waits: W2 = 8; else 4.
// ---------------------------------------------------------------------------
__global__ __launch_bounds__(768, 1) void lstm2r_k(
    const float* __restrict__ hin, const float* __restrict__ cin,
    const unsigned short* __restrict__ f_all2, const float* __restrict__ xgq,
    unsigned short* __restrict__ y2, float* __restrict__ h2T,
    float* __restrict__ hcar, float* __restrict__ ccar,
    int t0, int last){
  __shared__ alignas(16) unsigned short h_s[2][16][200];
  __shared__ alignas(16) unsigned short wbuf[3][48*512];
  int tid = threadIdx.x;
  int w = tid >> 6, l = tid & 63;
  int blk = blockIdx.x, b0 = blk*ROWS_;
  int m = l & 15, g4 = l >> 4, m0 = g4*4;
  int col = w*16 + m;
  // all-thread y2 store mapping: 8B per thread per level
  int srow = tid / 48, scs = (tid % 48) * 4;

  auto issue2 = [&](int gidx){
    int src = gidx % 6;                 // weights cycle every step (6 chunks)
    int buf = gidx % 3;                 // ring slot
    const unsigned short* g = f_all2 + (size_t)src*48*512 + (size_t)(w*4)*512 + (size_t)l*8;
    unsigned short* lp = &wbuf[buf][(w*4)*512];
    #pragma unroll
    for (int r=0; r<4; r++)
      __builtin_amdgcn_global_load_lds(AS1(g + r*512), AS3(lp + r*512), 16, 0, 0);
  };

  float c[4];
  #pragma unroll
  for (int r=0; r<4; r++){
    c[r] = cin[(size_t)(b0+m0+r)*192 + col];
    h_s[0][m0+r][col] = f2bf(hin[(size_t)(b0+m0+r)*192 + col]);
  }
  const f32x4* xp = (const f32x4*)xgq + (size_t)blk*QLEV_*48*64;
  f32x4 xg[4], xgn[4];
  #pragma unroll
  for (int g=0; g<4; g++) xg[g] = xp[(size_t)(12*g + w)*64 + l];
  issue2(0);
  issue2(1);
  __syncthreads();                     // full drain

  int gc = 0;
  for (int tl=0; tl<QLEV_; tl++){
    int cur = tl & 1;
    f32x4 acc[4];
    #pragma unroll
    for (int g=0; g<4; g++) acc[g] = xg[g];
    #pragma unroll
    for (int ch=0; ch<6; ch++){
      if (ch == 2) asm volatile("s_waitcnt vmcnt(8) lgkmcnt(0)" ::: "memory");
      else         asm volatile("s_waitcnt vmcnt(4) lgkmcnt(0)" ::: "memory");
      __builtin_amdgcn_s_barrier();
      asm volatile("" ::: "memory");
      issue2(gc+2);
      if (ch == 1){
        // extras (uniform all waves): xg prefetch (4 loads) + deferred y2 store
        int tln = (tl < QLEV_-1) ? tl+1 : tl;
        #pragma unroll
        for (int g=0; g<4; g++) xgn[g] = xp[((size_t)tln*48 + 12*g + w)*64 + l];
        int tprev = (tl > 0) ? tl-1 : 0;
        int lev = t0 + tprev;          // tl=0 dummy -> level t0 (overwritten at tl=1)
        s4_ v = *(const s4_*)&h_s[tl & 1][srow][scs];
        *(s4_*)(y2 + ((size_t)(b0+srow)*NLEV_ + lev)*192 + scs) = v;
      }
      const short8* wb = (const short8*)&wbuf[gc%3][0];
      short8 ah = *(const short8*)&h_s[cur][m][ch*32 + g4*8];
      #pragma unroll
      for (int g=0; g<4; g++)
        acc[g] = __builtin_amdgcn_mfma_f32_16x16x32_bf16(ah, wb[(12*g + w)*64 + l], acc[g], 0, 0, 0);
      gc++;
    }
    float hf[4];
    #pragma unroll
    for (int r=0; r<4; r++){
      float gi=acc[0][r], gf=acc[1][r], gg=acc[2][r], go=acc[3][r];
      float cn = sigm_(gf)*c[r] + sigm_(gi)*tanh_(gg);
      float hn = sigm_(go)*tanh_(cn);
      c[r] = cn;
      hf[r] = hn;
      h_s[cur^1][m0+r][col] = f2bf(hn);
    }
    if (tl == QLEV_-1){
      #pragma unroll
      for (int r=0; r<4; r++){
        hcar[(size_t)(b0+m0+r)*192 + col] = hf[r];
        ccar[(size_t)(b0+m0+r)*192 + col] = c[r];
      }
      if (last){
        #pragma unroll
        for (int r=0; r<4; r++) h2T[(size_t)(b0+m0+r)*192 + col] = hf[r];
      }
    }
    #pragma unroll
    for (int g=0; g<4; g++) xg[g] = xgn[g];
  }
  softbar();
  // final deferred y2 store: step QLEV_-1's h (in h_s[QLEV_&1]) -> level t0+QLEV_-1
  {
    s4_ v = *(const s4_*)&h_s[QLEV_ & 1][srow][scs];
    *(s4_*)(y2 + ((size_t)(b0+srow)*NLEV_ + (t0 + QLEV_-1))*192 + scs) = v;
  }
}

// ---------------------------------------------------------------------------
// heads
// ---------------------------------------------------------------------------
__global__ void heads_k(const unsigned short* __restrict__ y2, const float* __restrict__ Wc,
                        const float* __restrict__ outb, const float* __restrict__ yscale_lev,
                        float* __restrict__ out){
  __shared__ alignas(16) unsigned short yl[48][200];   // padded rows (400B)
  int tid = threadIdx.x;
  int row0 = blockIdx.x*48;
  for (int ci = tid; ci < 48*24; ci += 256){
    int r = ci/24, cgi = ci%24;
    short8 v = *(const short8*)(y2 + ((size_t)(row0+r))*192 + cgi*8);
    *(short8*)&yl[r][cgi*8] = v;
  }
  __syncthreads();
  if (tid < 240){
    int r = tid/5, n = tid - 5*r;
    int row = row0 + r;
    float acc = outb[n];
    const float* wc = Wc + n*192;
    #pragma unroll
    for (int cgi=0; cgi<24; cgi++){
      short8 y8 = *(const short8*)&yl[r][cgi*8];
      #pragma unroll
      for (int j=0;j<8;j++) acc += bf2f((unsigned short)y8[j]) * wc[cgi*8+j];
    }
    int lev = row % NLEV_;
    out[(size_t)row*5 + n] = acc / yscale_lev[lev*5 + n];
  }
}

// ---------------------------------------------------------------------------
// sfc
// ---------------------------------------------------------------------------
__global__ void sfc_k(const float* __restrict__ h2T, const float* __restrict__ W_sfco,
                      const float* __restrict__ b_sfco, const float* __restrict__ yscale_sca,
                      float* __restrict__ out_sfc){
  int t = blockIdx.x*256 + threadIdx.x;
  if (t >= B_*2) return;
  int b = t >> 1, j = t & 1;
  float acc = b_sfco[j];
  for (int k=0;k<192;k++) acc += h2T[(size_t)b*192+k] * W_sfco[j*192+k];
  out_sfc[t] = acc / yscale_sca[j];
}

// ---------------------------------------------------------------------------
extern "C" void kernel_launch(void* const* d_in, const int* in_sizes, int n_in,
                              void* d_out, int out_size, void* d_ws, size_t ws_size,
                              hipStream_t stream){
  const float* x_lev     = (const float*)d_in[0];
  const float* x_sfc     = (const float*)d_in[1];
  const float* memory_   = (const float*)d_in[2];
  const float* xmean_lev = (const float*)d_in[3];
  const float* xdiv_lev  = (const float*)d_in[4];
  const float* xmean_sca = (const float*)d_in[5];
  const float* xdiv_sca  = (const float*)d_in[6];
  const float* yscale_lev= (const float*)d_in[7];
  const float* yscale_sca= (const float*)d_in[8];
  const float* W_sfc1    = (const float*)d_in[9];
  const float* b_sfc1    = (const float*)d_in[10];
  const float* W_sfc2    = (const float*)d_in[11];
  const float* b_sfc2    = (const float*)d_in[12];
  const float* W_toa1    = (const float*)d_in[13];
  const float* b_toa1    = (const float*)d_in[14];
  const float* W_toa2    = (const float*)d_in[15];
  const float* b_toa2    = (const float*)d_in[16];
  const float* W_ih1     = (const float*)d_in[17];
  const float* W_hh1     = (const float*)d_in[18];
  const float* b_1       = (const float*)d_in[19];
  const float* W_ih2     = (const float*)d_in[20];
  const float* W_hh2     = (const float*)d_in[21];
  const float* b_2       = (const float*)d_in[22];
  const float* W_lat     = (const float*)d_in[23];
  const float* b_lat     = (const float*)d_in[24];
  const float* W_out     = (const float*)d_in[25];
  const float* b_out     = (const float*)d_in[26];
  const float* W_sfco    = (const float*)d_in[27];
  const float* b_sfco    = (const float*)d_in[28];

  char* ws = (char*)d_ws;
  float* h0            = (float*)(ws + 0);
  float* c0            = (float*)(ws + 786432);
  float* h0b           = (float*)(ws + 1572864);
  float* c0b           = (float*)(ws + 2359296);
  unsigned short* f_all1=(unsigned short*)(ws + 3145728);  // 344064 B
  unsigned short* f_all2=(unsigned short*)(ws + 3489792);  // 294912 B
  unsigned short* f_ih2= (unsigned short*)(ws + 3784704);  // 294912 B
  unsigned short* xfrag= (unsigned short*)(ws + 4079616);
  unsigned short* y1frag=(unsigned short*)(ws + 8011776);
  unsigned short* y2   = (unsigned short*)(ws + 31604736);
  float* h2T           = (float*)(ws + 55197696);
  float* Wc            = (float*)(ws + 55984128);
  float* outb          = (float*)(ws + 55987968);
  float* hcar          = (float*)(ws + 55988224);
  float* ccar          = (float*)(ws + 56774656);
  float* xgq           = (float*)(ws + 57561088);   // 47,185,920 B

  float* out    = (float*)d_out;
  float* outsfc = out + (size_t)B_*NLEV_*5;

  prep_weights_k<<<228, 256, 0, stream>>>(W_hh1, W_ih1, W_hh2, W_ih2, f_all1, f_all2, f_ih2);
  wc_k<<<4, 256, 0, stream>>>(W_lat, b_lat, W_out, b_out, Wc, outb);
  prep_x_k<<<960, 256, 0, stream>>>(x_lev, xmean_lev, xdiv_lev, memory_, xfrag);
  init_states_k<<<768, 256, 0, stream>>>(x_sfc, xmean_sca, xdiv_sca,
                                         W_sfc1, b_sfc1, W_sfc2, b_sfc2,
                                         W_toa1, b_toa1, W_toa2, b_toa2,
                                         h0, c0, h0b, c0b);
  lstm1_k<<<NBLK_, 768, 0, stream>>>(h0, c0, f_all1, xfrag, b_1, y1frag);
  for (int q = 0; q < 4; q++){
    xg_gemm_k<<<320, 768, 0, stream>>>(y1frag, f_ih2, b_2, xgq, q*QLEV_);
    lstm2r_k<<<NBLK_, 768, 0, stream>>>(q == 0 ? h0b : hcar, q == 0 ? c0b : ccar,
                                        f_all2, xgq, y2, h2T, hcar, ccar,
                                        q*QLEV_, q == 3 ? 1 : 0);
  }
  heads_k<<<1280, 256, 0, stream>>>(y2, Wc, outb, yscale_lev, out);
  sfc_k<<<8, 256, 0, stream>>>(h2T, W_sfco, b_sfco, yscale_sca, outsfc);
}

// Round 22
// 338.993 us; speedup vs baseline: 1.8607x; 1.8607x over previous
//
#include <hip/hip_runtime.h>
#include <hip/hip_bf16.h>

using short8 = __attribute__((ext_vector_type(8))) short;
using f32x4  = __attribute__((ext_vector_type(4))) float;

// Problem dims
#define B_     1024
#define NLEV_  60
#define NBLK_  64     // batch blocks for LSTM kernels
#define ROWS_  16     // batch rows per block
#define QLEV_  15     // levels per lstm2 quarter

__device__ __forceinline__ float bf2f(unsigned short u){
  unsigned int v = ((unsigned int)u) << 16;
  return __builtin_bit_cast(float, v);
}
__device__ __forceinline__ unsigned short f2bf(float x){
  __hip_bfloat16 h = __float2bfloat16(x);
  return __builtin_bit_cast(unsigned short, h);
}
__device__ __forceinline__ float sigm_(float x){
  return __builtin_amdgcn_rcpf(1.0f + __expf(-x));
}
__device__ __forceinline__ float tanh_(float x){
  return 1.0f - 2.0f*__builtin_amdgcn_rcpf(1.0f + __expf(2.0f*x));
}
// Barrier that does NOT drain vmcnt: LDS-visibility only.
__device__ __forceinline__ void softbar(){
  asm volatile("s_waitcnt lgkmcnt(0)" ::: "memory");
  __builtin_amdgcn_s_barrier();
  asm volatile("" ::: "memory");
}

// ---------------------------------------------------------------------------
// prep_weights: f32 -> bf16 MFMA B-frag layout. Frag (nt,kf): lane l holds
// W[n=16nt+(l&15)][k=32kf+8*(l>>4)+j], j=0..7.
// ---------------------------------------------------------------------------
__global__ void prep_weights_k(const float* __restrict__ Whh1, const float* __restrict__ Wih1,
                               const float* __restrict__ Whh2, const float* __restrict__ Wih2,
                               unsigned short* __restrict__ f_hh1, unsigned short* __restrict__ f_ih1,
                               unsigned short* __restrict__ f_hh2, unsigned short* __restrict__ f_ih2){
  int t = blockIdx.x*256 + threadIdx.x;
  if (t >= 912*64) return;
  int lane = t & 63;
  int fr   = t >> 6;
  int m    = lane & 15;
  int g16  = lane >> 4;
  short8 sv;
  unsigned short* dst;
  if (fr < 288){                    // Whh1 768x192
    int nt = fr/6, kf = fr%6;
    int n = nt*16 + m, k0 = kf*32 + g16*8;
    #pragma unroll
    for (int j=0;j<8;j++) sv[j] = (short)f2bf(Whh1[n*192 + k0 + j]);
    dst = f_hh1 + (size_t)(fr*64 + lane)*8;
  } else if (fr < 336){             // Wih1 768x28 (pad K to 32)
    int nt = fr - 288;
    int n = nt*16 + m, k0 = g16*8;
    #pragma unroll
    for (int j=0;j<8;j++){
      int k = k0 + j;
      sv[j] = (short)((k < 28) ? f2bf(Wih1[n*28 + k]) : (unsigned short)0);
    }
    dst = f_ih1 + (size_t)(nt*64 + lane)*8;
  } else if (fr < 624){             // Whh2 768x192
    int fl = fr - 336;
    int nt = fl/6, kf = fl%6;
    int n = nt*16 + m, k0 = kf*32 + g16*8;
    #pragma unroll
    for (int j=0;j<8;j++) sv[j] = (short)f2bf(Whh2[n*192 + k0 + j]);
    dst = f_hh2 + (size_t)(fl*64 + lane)*8;
  } else {                          // Wih2 768x192
    int fl = fr - 624;
    int nt = fl/6, kf = fl%6;
    int n = nt*16 + m, k0 = kf*32 + g16*8;
    #pragma unroll
    for (int j=0;j<8;j++) sv[j] = (short)f2bf(Wih2[n*192 + k0 + j]);
    dst = f_ih2 + (size_t)(fl*64 + lane)*8;
  }
  *(short8*)dst = sv;
}

// ---------------------------------------------------------------------------
// wc_k: fold output projections: Wc = W_out @ W_lat (5x192), outb = b_out +
// W_out @ b_lat.
// ---------------------------------------------------------------------------
__global__ void wc_k(const float* __restrict__ W_lat, const float* __restrict__ b_lat,
                     const float* __restrict__ W_out, const float* __restrict__ b_out,
                     float* __restrict__ Wc, float* __restrict__ outb){
  int t = blockIdx.x*256 + threadIdx.x;
  if (t < 960){
    int n = t / 192, k = t % 192;
    float a = 0.f;
    #pragma unroll
    for (int j=0;j<16;j++) a += W_out[n*16+j] * W_lat[j*192+k];
    Wc[t] = a;
  } else if (t < 965){
    int n = t - 960;
    float a = b_out[n];
    #pragma unroll
    for (int j=0;j<16;j++) a += W_out[n*16+j] * b_lat[j];
    outb[n] = a;
  }
}

// ---------------------------------------------------------------------------
// prep_x: x_main = [(x_lev[:,:, :12]-mean)/div, memory] (28 ch pad 32), bf16
// A-frag layout [blk][lev][lane].
// ---------------------------------------------------------------------------
__global__ void prep_x_k(const float* __restrict__ x_lev, const float* __restrict__ xmean_lev,
                         const float* __restrict__ xdiv_lev, const float* __restrict__ memv,
                         unsigned short* __restrict__ xfrag){
  int t = blockIdx.x*256 + threadIdx.x;
  if (t >= NBLK_*NLEV_*64) return;
  int lane = t & 63;
  int lev  = (t >> 6) % NLEV_;
  int blk  = t / (NLEV_*64);
  int m    = lane & 15;
  int b    = blk*ROWS_ + m;
  int k0   = (lane >> 4)*8;
  short8 sv;
  #pragma unroll
  for (int j=0;j<8;j++){
    int k = k0 + j;
    float val = 0.0f;
    if (k < 12)      val = (x_lev[(size_t)(b*NLEV_+lev)*15 + k] - xmean_lev[lev*15+k]) / xdiv_lev[lev*15+k];
    else if (k < 28) val = memv[(size_t)(b*NLEV_+lev)*16 + (k-12)];
    sv[j] = (short)f2bf(val);
  }
  *(short8*)(xfrag + (size_t)((blk*NLEV_+lev)*64 + lane)*8) = sv;
}

// ---------------------------------------------------------------------------
// init_states
// ---------------------------------------------------------------------------
__global__ void init_states_k(const float* __restrict__ x_sfc, const float* __restrict__ xmean_sca,
                              const float* __restrict__ xdiv_sca,
                              const float* __restrict__ Ws1, const float* __restrict__ bs1,
                              const float* __restrict__ Ws2, const float* __restrict__ bs2,
                              const float* __restrict__ Wt1, const float* __restrict__ bt1,
                              const float* __restrict__ Wt2, const float* __restrict__ bt2,
                              float* __restrict__ h0, float* __restrict__ c0,
                              float* __restrict__ h0b, float* __restrict__ c0b){
  int t = blockIdx.x*256 + threadIdx.x;
  if (t >= B_*192) return;
  int b = t / 192, n = t % 192;
  float a1 = bs1[n], a2 = bs2[n];
  for (int j=0;j<19;j++){
    float xs = (x_sfc[b*24+j] - xmean_sca[j]) / xdiv_sca[j];
    a1 += xs * Ws1[n*19+j];
    a2 += xs * Ws2[n*19+j];
  }
  h0[t] = tanh_(a1); c0[t] = tanh_(a2);
  float a3 = bt1[n], a4 = bt2[n];
  for (int j=0;j<2;j++){
    float xt = (x_sfc[b*24+j] - xmean_sca[j]) / xdiv_sca[j];
    a3 += xt * Wt1[n*2+j];
    a4 += xt * Wt2[n*2+j];
  }
  h0b[t] = tanh_(a3); c0b[t] = tanh_(a4);
}

// ---------------------------------------------------------------------------
// lstm1: persistent reverse LSTM. 64 blocks x 12 waves, 1 block/CU.
// Structural note (r8-r21): per-CU weight ingest saturates at ~85 B/cy
// (~10 outstanding 1KB loads / ~120cy L2 latency); 344 KB/step -> ~4100
// cy/step is the floor for this decomposition. VGPR-resident weights
// (6 attempts), half/full-LDS staging, and a DMA LDS-ring all failed to
// beat the compiler's natural L2-stream schedule below.
// ---------------------------------------------------------------------------
__global__ __launch_bounds__(768)
__attribute__((amdgpu_waves_per_eu(3,3)))
void lstm1_k(
    const float* __restrict__ h0, const float* __restrict__ c0,
    const unsigned short* __restrict__ f_hh1, const unsigned short* __restrict__ f_ih1,
    const unsigned short* __restrict__ xfrag, const float* __restrict__ b1,
    unsigned short* __restrict__ y1frag){
  __shared__ alignas(16) unsigned short h_s[2][16][200];
  int tid = threadIdx.x;
  int w = tid >> 6, l = tid & 63;
  int blk = blockIdx.x, b0 = blk*ROWS_;
  int m = l & 15, g4 = l >> 4, m0 = g4*4;
  int col = w*16 + m;

  const short8* whh_p = (const short8*)f_hh1;
  const short8* wih_p = (const short8*)f_ih1;
  short8 whh[4][6], wih[4];
  #pragma unroll
  for (int g=0; g<4; g++){
    int nt = 12*g + w;
    wih[g] = wih_p[nt*64 + l];
    #pragma unroll
    for (int kf=0; kf<6; kf++) whh[g][kf] = whh_p[(nt*6 + kf)*64 + l];
  }
  float bias[4];
  #pragma unroll
  for (int g=0; g<4; g++) bias[g] = b1[g*192 + col];
  float c[4];
  #pragma unroll
  for (int r=0; r<4; r++){
    c[r] = c0[(size_t)(b0+m0+r)*192 + col];
    h_s[0][m0+r][col] = f2bf(h0[(size_t)(b0+m0+r)*192 + col]);
  }
  __syncthreads();

  const short8* xfp = (const short8*)xfrag + (size_t)blk*NLEV_*64;
  short8 ax = xfp[(NLEV_-1)*64 + l];   // level for t=0
  for (int t=0; t<NLEV_; t++){
    int cur = t & 1;
    int lsrc = NLEV_-1 - t;
    short8 ax_n = xfp[(lsrc > 0 ? lsrc-1 : 0)*64 + l];   // prefetch next level
    f32x4 acc[4];
    #pragma unroll
    for (int g=0; g<4; g++){ acc[g][0]=bias[g]; acc[g][1]=bias[g]; acc[g][2]=bias[g]; acc[g][3]=bias[g]; }
    #pragma unroll
    for (int g=0; g<4; g++)
      acc[g] = __builtin_amdgcn_mfma_f32_16x16x32_bf16(ax, wih[g], acc[g], 0, 0, 0);
    #pragma unroll
    for (int kf=0; kf<6; kf++){
      short8 ah = *(const short8*)&h_s[cur][m][kf*32 + g4*8];
      #pragma unroll
      for (int g=0; g<4; g++)
        acc[g] = __builtin_amdgcn_mfma_f32_16x16x32_bf16(ah, whh[g][kf], acc[g], 0, 0, 0);
    }
    #pragma unroll
    for (int r=0; r<4; r++){
      float gi=acc[0][r], gf=acc[1][r], gg=acc[2][r], go=acc[3][r];
      float cn = sigm_(gf)*c[r] + sigm_(gi)*tanh_(gg);
      float hn = sigm_(go)*tanh_(cn);
      c[r] = cn;
      h_s[cur^1][m0+r][col] = f2bf(hn);
    }
    softbar();
    // coalesced y1frag store: wave w<6 emits frag kf=w of level lsrc
    if (w < 6){
      short8 v = *(const short8*)&h_s[cur^1][m][w*32 + g4*8];
      *(short8*)(y1frag + ((size_t)(blk*NLEV_+lsrc)*6 + w)*512 + (size_t)l*8) = v;
    }
    ax = ax_n;
  }
}

// ---------------------------------------------------------------------------
// xg_gemm: batch-parallel xg2 = y1 @ W_ih2^T + b2 for QLEV_ levels starting
// at lev0. Output in MFMA C-frag layout. 320 blocks x 12 waves; each block
// does 3 levels.
// ---------------------------------------------------------------------------
__global__ __launch_bounds__(768)
__attribute__((amdgpu_waves_per_eu(3,3)))
void xg_gemm_k(
    const unsigned short* __restrict__ y1frag, const unsigned short* __restrict__ f_ih2,
    const float* __restrict__ b2, float* __restrict__ xgq, int lev0){
  int tid = threadIdx.x;
  int w = tid >> 6, l = tid & 63;
  int blk = blockIdx.x / 5, lg = blockIdx.x % 5;
  const short8* yfp   = (const short8*)y1frag;
  const short8* wih_p = (const short8*)f_ih2;
  f32x4 acc[3][4];
  #pragma unroll
  for (int g=0; g<4; g++){
    float bv = b2[g*192 + 16*w + (l&15)];
    #pragma unroll
    for (int j=0; j<3; j++){ acc[j][g][0]=bv; acc[j][g][1]=bv; acc[j][g][2]=bv; acc[j][g][3]=bv; }
  }
  #pragma unroll
  for (int kf=0; kf<6; kf++){
    short8 wb[4];
    #pragma unroll
    for (int g=0; g<4; g++) wb[g] = wih_p[((12*g + w)*6 + kf)*64 + l];
    #pragma unroll
    for (int j=0; j<3; j++){
      short8 ay = yfp[((size_t)(blk*NLEV_ + lev0 + lg*3 + j)*6 + kf)*64 + l];
      #pragma unroll
      for (int g=0; g<4; g++)
        acc[j][g] = __builtin_amdgcn_mfma_f32_16x16x32_bf16(ay, wb[g], acc[j][g], 0, 0, 0);
    }
  }
  #pragma unroll
  for (int j=0; j<3; j++){
    int tl = lg*3 + j;
    #pragma unroll
    for (int g=0; g<4; g++)
      *(f32x4*)&xgq[(((size_t)blk*QLEV_ + tl)*48 + 12*g + w)*256 + (size_t)l*4] = acc[j][g];
  }
}

// ---------------------------------------------------------------------------
// lstm2r: recurrent-only forward LSTM over QLEV_ steps. Whh2 streamed from
// L2 by the compiler's natural schedule; gate input xg pre-computed (bias
// folded), prefetched one step ahead.
// ---------------------------------------------------------------------------
__global__ __launch_bounds__(768)
__attribute__((amdgpu_waves_per_eu(3,3)))
void lstm2r_k(
    const float* __restrict__ hin, const float* __restrict__ cin,
    const unsigned short* __restrict__ f_hh2, const float* __restrict__ xgq,
    unsigned short* __restrict__ y2, float* __restrict__ h2T,
    float* __restrict__ hcar, float* __restrict__ ccar,
    int t0, int last){
  __shared__ alignas(16) unsigned short h_s[2][16][200];
  int tid = threadIdx.x;
  int w = tid >> 6, l = tid & 63;
  int blk = blockIdx.x, b0 = blk*ROWS_;
  int m = l & 15, g4 = l >> 4, m0 = g4*4;
  int col = w*16 + m;
  int row_ = (w*64 + l)/24, cg_ = (w*64 + l)%24;   // y2 store assignment (w<6)

  const short8* whh_p = (const short8*)f_hh2;
  short8 whh[4][6];
  #pragma unroll
  for (int g=0; g<4; g++){
    int nt = 12*g + w;
    #pragma unroll
    for (int kf=0; kf<6; kf++) whh[g][kf] = whh_p[(nt*6 + kf)*64 + l];
  }
  float c[4];
  #pragma unroll
  for (int r=0; r<4; r++){
    c[r] = cin[(size_t)(b0+m0+r)*192 + col];
    h_s[0][m0+r][col] = f2bf(hin[(size_t)(b0+m0+r)*192 + col]);
  }
  __syncthreads();

  const f32x4* xp = (const f32x4*)xgq + (size_t)blk*QLEV_*48*64;
  f32x4 xg[4], xgn[4];
  #pragma unroll
  for (int g=0; g<4; g++) xg[g] = xp[(size_t)(12*g + w)*64 + l];

  for (int tl=0; tl<QLEV_; tl++){
    int cur = tl & 1;
    int tln = (tl < QLEV_-1) ? tl+1 : tl;
    #pragma unroll
    for (int g=0; g<4; g++) xgn[g] = xp[((size_t)tln*48 + 12*g + w)*64 + l];

    f32x4 acc[4];
    #pragma unroll
    for (int g=0; g<4; g++) acc[g] = xg[g];
    #pragma unroll
    for (int kf=0; kf<6; kf++){
      short8 ah = *(const short8*)&h_s[cur][m][kf*32 + g4*8];
      #pragma unroll
      for (int g=0; g<4; g++)
        acc[g] = __builtin_amdgcn_mfma_f32_16x16x32_bf16(ah, whh[g][kf], acc[g], 0, 0, 0);
    }
    float hf[4];
    #pragma unroll
    for (int r=0; r<4; r++){
      float gi=acc[0][r], gf=acc[1][r], gg=acc[2][r], go=acc[3][r];
      float cn = sigm_(gf)*c[r] + sigm_(gi)*tanh_(gg);
      float hn = sigm_(go)*tanh_(cn);
      c[r] = cn;
      hf[r] = hn;
      h_s[cur^1][m0+r][col] = f2bf(hn);
    }
    if (tl == QLEV_-1){
      #pragma unroll
      for (int r=0; r<4; r++){
        hcar[(size_t)(b0+m0+r)*192 + col] = hf[r];
        ccar[(size_t)(b0+m0+r)*192 + col] = c[r];
      }
      if (last){
        #pragma unroll
        for (int r=0; r<4; r++) h2T[(size_t)(b0+m0+r)*192 + col] = hf[r];
      }
    }
    softbar();
    // coalesced y2 store: waves 0-5, 16 rows x 24 col-groups of 16B
    if (w < 6){
      int t = t0 + tl;
      short8 v = *(const short8*)&h_s[cur^1][row_][cg_*8];
      *(short8*)(y2 + ((size_t)(b0+row_)*NLEV_ + t)*192 + cg_*8) = v;
    }
    #pragma unroll
    for (int g=0; g<4; g++) xg[g] = xgn[g];
  }
}

// ---------------------------------------------------------------------------
// heads: out[row][n] = (y2[row] . Wc[n] + outb[n]) / yscale_lev[lev][n]
// ---------------------------------------------------------------------------
__global__ void heads_k(const unsigned short* __restrict__ y2, const float* __restrict__ Wc,
                        const float* __restrict__ outb, const float* __restrict__ yscale_lev,
                        float* __restrict__ out){
  __shared__ alignas(16) unsigned short yl[48][200];   // padded rows (400B)
  int tid = threadIdx.x;
  int row0 = blockIdx.x*48;
  for (int ci = tid; ci < 48*24; ci += 256){
    int r = ci/24, cgi = ci%24;
    short8 v = *(const short8*)(y2 + ((size_t)(row0+r))*192 + cgi*8);
    *(short8*)&yl[r][cgi*8] = v;
  }
  __syncthreads();
  if (tid < 240){
    int r = tid/5, n = tid - 5*r;
    int row = row0 + r;
    float acc = outb[n];
    const float* wc = Wc + n*192;
    #pragma unroll
    for (int cgi=0; cgi<24; cgi++){
      short8 y8 = *(const short8*)&yl[r][cgi*8];
      #pragma unroll
      for (int j=0;j<8;j++) acc += bf2f((unsigned short)y8[j]) * wc[cgi*8+j];
    }
    int lev = row % NLEV_;
    out[(size_t)row*5 + n] = acc / yscale_lev[lev*5 + n];
  }
}

// ---------------------------------------------------------------------------
// sfc
// ---------------------------------------------------------------------------
__global__ void sfc_k(const float* __restrict__ h2T, const float* __restrict__ W_sfco,
                      const float* __restrict__ b_sfco, const float* __restrict__ yscale_sca,
                      float* __restrict__ out_sfc){
  int t = blockIdx.x*256 + threadIdx.x;
  if (t >= B_*2) return;
  int b = t >> 1, j = t & 1;
  float acc = b_sfco[j];
  for (int k=0;k<192;k++) acc += h2T[(size_t)b*192+k] * W_sfco[j*192+k];
  out_sfc[t] = acc / yscale_sca[j];
}

// ---------------------------------------------------------------------------
extern "C" void kernel_launch(void* const* d_in, const int* in_sizes, int n_in,
                              void* d_out, int out_size, void* d_ws, size_t ws_size,
                              hipStream_t stream){
  const float* x_lev     = (const float*)d_in[0];
  const float* x_sfc     = (const float*)d_in[1];
  const float* memory_   = (const float*)d_in[2];
  const float* xmean_lev = (const float*)d_in[3];
  const float* xdiv_lev  = (const float*)d_in[4];
  const float* xmean_sca = (const float*)d_in[5];
  const float* xdiv_sca  = (const float*)d_in[6];
  const float* yscale_lev= (const float*)d_in[7];
  const float* yscale_sca= (const float*)d_in[8];
  const float* W_sfc1    = (const float*)d_in[9];
  const float* b_sfc1    = (const float*)d_in[10];
  const float* W_sfc2    = (const float*)d_in[11];
  const float* b_sfc2    = (const float*)d_in[12];
  const float* W_toa1    = (const float*)d_in[13];
  const float* b_toa1    = (const float*)d_in[14];
  const float* W_toa2    = (const float*)d_in[15];
  const float* b_toa2    = (const float*)d_in[16];
  const float* W_ih1     = (const float*)d_in[17];
  const float* W_hh1     = (const float*)d_in[18];
  const float* b_1       = (const float*)d_in[19];
  const float* W_ih2     = (const float*)d_in[20];
  const float* W_hh2     = (const float*)d_in[21];
  const float* b_2       = (const float*)d_in[22];
  const float* W_lat     = (const float*)d_in[23];
  const float* b_lat     = (const float*)d_in[24];
  const float* W_out     = (const float*)d_in[25];
  const float* b_out     = (const float*)d_in[26];
  const float* W_sfco    = (const float*)d_in[27];
  const float* b_sfco    = (const float*)d_in[28];

  char* ws = (char*)d_ws;
  float* h0            = (float*)(ws + 0);
  float* c0            = (float*)(ws + 786432);
  float* h0b           = (float*)(ws + 1572864);
  float* c0b           = (float*)(ws + 2359296);
  unsigned short* f_hh1= (unsigned short*)(ws + 3145728);
  unsigned short* f_ih1= (unsigned short*)(ws + 3440640);
  unsigned short* f_hh2= (unsigned short*)(ws + 3489792);
  unsigned short* f_ih2= (unsigned short*)(ws + 3784704);
  unsigned short* xfrag= (unsigned short*)(ws + 4079616);
  unsigned short* y1frag=(unsigned short*)(ws + 8011776);
  unsigned short* y2   = (unsigned short*)(ws + 31604736);
  float* h2T           = (float*)(ws + 55197696);
  float* Wc            = (float*)(ws + 55984128);
  float* outb          = (float*)(ws + 55987968);
  float* hcar          = (float*)(ws + 55988224);
  float* ccar          = (float*)(ws + 56774656);
  float* xgq           = (float*)(ws + 57561088);   // 1024*15*768*4 = 47,185,920 B

  float* out    = (float*)d_out;
  float* outsfc = out + (size_t)B_*NLEV_*5;

  prep_weights_k<<<228, 256, 0, stream>>>(W_hh1, W_ih1, W_hh2, W_ih2, f_hh1, f_ih1, f_hh2, f_ih2);
  wc_k<<<4, 256, 0, stream>>>(W_lat, b_lat, W_out, b_out, Wc, outb);
  prep_x_k<<<960, 256, 0, stream>>>(x_lev, xmean_lev, xdiv_lev, memory_, xfrag);
  init_states_k<<<768, 256, 0, stream>>>(x_sfc, xmean_sca, xdiv_sca,
                                         W_sfc1, b_sfc1, W_sfc2, b_sfc2,
                                         W_toa1, b_toa1, W_toa2, b_toa2,
                                         h0, c0, h0b, c0b);
  lstm1_k<<<NBLK_, 768, 0, stream>>>(h0, c0, f_hh1, f_ih1, xfrag, b_1, y1frag);
  for (int q = 0; q < 4; q++){
    xg_gemm_k<<<320, 768, 0, stream>>>(y1frag, f_ih2, b_2, xgq, q*QLEV_);
    lstm2r_k<<<NBLK_, 768, 0, stream>>>(q == 0 ? h0b : hcar, q == 0 ? c0b : ccar,
                                        f_hh2, xgq, y2, h2T, hcar, ccar,
                                        q*QLEV_, q == 3 ? 1 : 0);
  }
  heads_k<<<1280, 256, 0, stream>>>(y2, Wc, outb, yscale_lev, out);
  sfc_k<<<8, 256, 0, stream>>>(h2T, W_sfco, b_sfco, yscale_sca, outsfc);
}